// Round 5
// baseline (711.830 us; speedup 1.0000x reference)
//
#include <hip/hip_runtime.h>
#include <math.h>

#define NDIM 256
#define VOL  (NDIM*NDIM*NDIM)      // 16777216 elements per batch-channel volume
#define NB   128                    // kept bins 0..127; label 128 is dropped
#define NSPREAD 16                  // spread copies for the global flush

// base-4 digit reversal of an 8-bit index (involution)
__device__ __forceinline__ int dr4(int x) {
    int b = (int)(__brev((unsigned)x) >> 24);
    return ((b >> 1) & 0x55) | ((b << 1) & 0xAA);
}
__device__ __forceinline__ float2 cmul(float2 a, float2 b) {
    return make_float2(a.x * b.x - a.y * b.y, a.x * b.y + a.y * b.x);
}
__device__ __forceinline__ float2 cadd(float2 a, float2 b){ return make_float2(a.x+b.x, a.y+b.y); }
__device__ __forceinline__ float2 csub(float2 a, float2 b){ return make_float2(a.x-b.x, a.y-b.y); }
__device__ __forceinline__ float2 cmuli_neg(float2 a){ return make_float2(a.y, -a.x); }  // -i*a
__device__ __forceinline__ float2 cmuli_pos(float2 a){ return make_float2(-a.y, a.x); }  // +i*a

// ---------------------------------------------------------------------------
// Pass 1: pack (ref + i*pred), radix-4 Stockham FFT along z. One WAVE per
// 256-pt line (wave-private LDS, no barriers). Natural-order output.
// ---------------------------------------------------------------------------
__global__ __launch_bounds__(256) void fftz_pack(const float* __restrict__ re_in,
                                                 const float* __restrict__ im_in,
                                                 float2* __restrict__ out)
{
    __shared__ float2 buf[4][2][NDIM];   // 16 KB, per-wave double buffer
    const int t = threadIdx.x;
    const int w = t >> 6, j = t & 63;
    const int L = blockIdx.x * 4 + w;    // line id in [0, 65536)
    const float* rp = re_in + (size_t)L * NDIM;
    const float* ip = im_in + (size_t)L * NDIM;

    float2 v0 = make_float2(rp[j      ], ip[j      ]);
    float2 v1 = make_float2(rp[j +  64], ip[j +  64]);
    float2 v2 = make_float2(rp[j + 128], ip[j + 128]);
    float2 v3 = make_float2(rp[j + 192], ip[j + 192]);

    // stage 0 (Ns=1, twiddle = 1)
    {
        float2 t0=cadd(v0,v2), t1=csub(v0,v2), t2=cadd(v1,v3), t3=csub(v1,v3);
        buf[w][0][4*j    ] = cadd(t0, t2);
        buf[w][0][4*j + 1] = cadd(t1, cmuli_neg(t3));
        buf[w][0][4*j + 2] = csub(t0, t2);
        buf[w][0][4*j + 3] = cadd(t1, cmuli_pos(t3));
    }
    __builtin_amdgcn_sched_barrier(0);

    int p = 0;
    #pragma unroll
    for (int stage = 1; stage <= 2; ++stage) {
        const int Ns = (stage == 1) ? 4 : 16;
        const int jm = j & (Ns - 1);
        float2 a0 = buf[w][p][j      ];
        float2 a1 = buf[w][p][j +  64];
        float2 a2 = buf[w][p][j + 128];
        float2 a3 = buf[w][p][j + 192];
        float sn, cs;
        __sincosf(-(float)(2.0 * M_PI) * (float)jm / (float)(4 * Ns), &sn, &cs);
        float2 w1 = make_float2(cs, sn);
        float2 w2 = cmul(w1, w1);
        float2 w3 = cmul(w2, w1);
        a1 = cmul(a1, w1); a2 = cmul(a2, w2); a3 = cmul(a3, w3);
        float2 t0=cadd(a0,a2), t1=csub(a0,a2), t2=cadd(a1,a3), t3=csub(a1,a3);
        const int idxD = (j / Ns) * (4 * Ns) + jm;
        buf[w][p^1][idxD         ] = cadd(t0, t2);
        buf[w][p^1][idxD +     Ns] = cadd(t1, cmuli_neg(t3));
        buf[w][p^1][idxD + 2 * Ns] = csub(t0, t2);
        buf[w][p^1][idxD + 3 * Ns] = cadd(t1, cmuli_pos(t3));
        p ^= 1;
        __builtin_amdgcn_sched_barrier(0);
    }

    // stage 3 (Ns=64): write straight to global
    {
        float2 a0 = buf[w][p][j      ];
        float2 a1 = buf[w][p][j +  64];
        float2 a2 = buf[w][p][j + 128];
        float2 a3 = buf[w][p][j + 192];
        float sn, cs;
        __sincosf(-(float)(2.0 * M_PI) * (float)j / 256.0f, &sn, &cs);
        float2 w1 = make_float2(cs, sn);
        float2 w2 = cmul(w1, w1);
        float2 w3 = cmul(w2, w1);
        a1 = cmul(a1, w1); a2 = cmul(a2, w2); a3 = cmul(a3, w3);
        float2 t0=cadd(a0,a2), t1=csub(a0,a2), t2=cadd(a1,a3), t3=csub(a1,a3);
        float2* op = out + (size_t)L * NDIM;
        op[j      ] = cadd(t0, t2);
        op[j +  64] = cadd(t1, cmuli_neg(t3));
        op[j + 128] = csub(t0, t2);
        op[j + 192] = cadd(t1, cmuli_pos(t3));
    }
}

// ---------------------------------------------------------------------------
// Pass 2: in-place radix-4 DIF FFT along y (stride 256). Tile 256 x 16 z,
// ld = 18 float2 (16B-aligned), float4 global I/O. Output dr4-ordered in y.
// ---------------------------------------------------------------------------
__global__ __launch_bounds__(256) void fft_strided(float2* __restrict__ A,
                                                   int lineStride, int outerStride)
{
    __shared__ float2 tile[NDIM * 18];   // 36.9 KB
    __shared__ float2 tw[NDIM];          // 2 KB
    const int t = threadIdx.x;
    {
        float sn, cs;
        __sincosf(-(float)(2.0 * M_PI) * (float)t / 256.0f, &sn, &cs);
        tw[t] = make_float2(cs, sn);
    }
    const int l4 = t & 7, u8 = t >> 3;
    const int o = blockIdx.x >> 4, c = blockIdx.x & 15;
    const long long base = (long long)o * outerStride + c * 16;

    #pragma unroll
    for (int it = 0; it < 8; ++it) {
        int pos = u8 + it * 32;
        const float4 d = *(const float4*)&A[base + (long long)pos * lineStride + 2 * l4];
        tile[pos * 18 + 2 * l4    ] = make_float2(d.x, d.y);
        tile[pos * 18 + 2 * l4 + 1] = make_float2(d.z, d.w);
    }
    __syncthreads();

    const int l = t & 15, u = t >> 4;
    #pragma unroll
    for (int ls = 6; ls >= 0; ls -= 2) {           // s = 64, 16, 4, 1
        const int s = 1 << ls;
        #pragma unroll
        for (int it = 0; it < 4; ++it) {
            int m  = u + it * 16;
            int jm = m & (s - 1);
            int bidx = ((m >> ls) << (ls + 2)) + jm;
            float2 a  = tile[(bidx        ) * 18 + l];
            float2 b  = tile[(bidx +     s) * 18 + l];
            float2 cc = tile[(bidx + 2 * s) * 18 + l];
            float2 d  = tile[(bidx + 3 * s) * 18 + l];
            float2 t0=cadd(a,cc), t1=csub(a,cc), t2=cadd(b,d), t3=csub(b,d);
            float2 y0 = cadd(t0, t2);
            float2 y1 = cadd(t1, cmuli_neg(t3));
            float2 y2 = csub(t0, t2);
            float2 y3 = cadd(t1, cmuli_pos(t3));
            int k1 = jm << (6 - ls);
            y1 = cmul(y1, tw[k1]);
            y2 = cmul(y2, tw[2 * k1]);
            y3 = cmul(y3, tw[3 * k1]);
            tile[(bidx        ) * 18 + l] = y0;
            tile[(bidx +     s) * 18 + l] = y1;
            tile[(bidx + 2 * s) * 18 + l] = y2;
            tile[(bidx + 3 * s) * 18 + l] = y3;
        }
        __syncthreads();
    }

    #pragma unroll
    for (int it = 0; it < 8; ++it) {
        int pos = u8 + it * 32;
        float2 e0 = tile[pos * 18 + 2 * l4], e1 = tile[pos * 18 + 2 * l4 + 1];
        *(float4*)&A[base + (long long)pos * lineStride + 2 * l4] =
            make_float4(e0.x, e0.y, e1.x, e1.y);
    }
}

// ---------------------------------------------------------------------------
// Pass 3 (fused): x-FFT + unpack + shell reduction. No volume write-back.
// Block = (fy, c): fy in [0,128) canonical y-frequency, c = z-chunk.
//   tile A: plane py=dr4(fy), z = (16c+1+zi)&255, zi in [0,16)  (partition of z)
//   tile B: plane pyp=dr4(256-fy), z = 240-16c+zi  (16B-aligned, = mirror of A)
// Partner of A(x, zi) is B(dr4(-fx), 15-zi): full -k conjugate in LDS.
// Weight 2 for fy in [1,127] (covers plane 256-fy), 1 for fy=0. fy=128 has
// label>=128 everywhere -> dropped. In-LDS radix-4 DIF x-FFT on both tiles,
// then per-wave LDS histograms, 16-way-spread global flush.
// ---------------------------------------------------------------------------
__global__ __launch_bounds__(256) void fft_x_reduce(const float2* __restrict__ A,
                                                    float* __restrict__ bins_s)
{
    __shared__ float2 tA[NDIM * 17];     // 34.8 KB
    __shared__ float2 tB[NDIM * 17];     // 34.8 KB
    __shared__ float2 tw[NDIM];          // 2 KB
    __shared__ float  bs[4][3 * NB];     // 6 KB
    const int t = threadIdx.x;
    const int w = t >> 6;
    const int fy = blockIdx.x >> 4, c = blockIdx.x & 15;
    const int py  = dr4(fy);
    const int pyp = dr4((256 - fy) & 255);
    const float wgt = (fy == 0) ? 1.f : 2.f;
    const int ay2 = fy * fy;

    {
        float sn, cs;
        __sincosf(-(float)(2.0 * M_PI) * (float)t / 256.0f, &sn, &cs);
        tw[t] = make_float2(cs, sn);
    }
    for (int i = t; i < 4 * 3 * NB; i += 256) ((float*)bs)[i] = 0.f;

    // ---- load tile A (float2, z-range shifted by +1) ----
    {
        const int zi = t & 15, u = t >> 4;
        const int z = (16 * c + 1 + zi) & 255;
        const long long off = (long long)py * 256 + z;
        #pragma unroll
        for (int it = 0; it < 16; ++it) {
            int pos = u + it * 16;
            tA[pos * 17 + zi] = A[(long long)pos * 65536 + off];
        }
    }
    // ---- load tile B (float4, aligned mirror range) ----
    {
        const int l4 = t & 7, u8 = t >> 3;
        const long long off = (long long)pyp * 256 + (240 - 16 * c);
        #pragma unroll
        for (int it = 0; it < 8; ++it) {
            int pos = u8 + it * 32;
            const float4 d = *(const float4*)&A[(long long)pos * 65536 + off + 2 * l4];
            tB[pos * 17 + 2 * l4    ] = make_float2(d.x, d.y);
            tB[pos * 17 + 2 * l4 + 1] = make_float2(d.z, d.w);
        }
    }
    __syncthreads();

    // ---- radix-4 DIF x-FFT on both tiles (stride 17) ----
    const int l = t & 15, u = t >> 4;
    #pragma unroll
    for (int ls = 6; ls >= 0; ls -= 2) {           // s = 64, 16, 4, 1
        const int s = 1 << ls;
        #pragma unroll
        for (int half = 0; half < 2; ++half) {
            float2* tile = half ? tB : tA;
            #pragma unroll
            for (int it = 0; it < 4; ++it) {
                int m  = u + it * 16;
                int jm = m & (s - 1);
                int bidx = ((m >> ls) << (ls + 2)) + jm;
                float2 a  = tile[(bidx        ) * 17 + l];
                float2 b  = tile[(bidx +     s) * 17 + l];
                float2 cc = tile[(bidx + 2 * s) * 17 + l];
                float2 d  = tile[(bidx + 3 * s) * 17 + l];
                float2 t0=cadd(a,cc), t1=csub(a,cc), t2=cadd(b,d), t3=csub(b,d);
                float2 y0 = cadd(t0, t2);
                float2 y1 = cadd(t1, cmuli_neg(t3));
                float2 y2 = csub(t0, t2);
                float2 y3 = cadd(t1, cmuli_pos(t3));
                int k1 = jm << (6 - ls);
                y1 = cmul(y1, tw[k1]);
                y2 = cmul(y2, tw[2 * k1]);
                y3 = cmul(y3, tw[3 * k1]);
                tile[(bidx        ) * 17 + l] = y0;
                tile[(bidx +     s) * 17 + l] = y1;
                tile[(bidx + 2 * s) * 17 + l] = y2;
                tile[(bidx + 3 * s) * 17 + l] = y3;
            }
        }
        __syncthreads();
    }

    // ---- unpack + shell accumulate over tile A ----
    {
        const int zi = l;
        const int z  = (16 * c + 1 + zi) & 255;
        const int az = (z < 128) ? z : 256 - z;
        const int r2yz = az * az + ay2;
        const int colp = 15 - zi;
        #pragma unroll
        for (int it = 0; it < 16; ++it) {
            int pos = u + it * 16;
            int fx = dr4(pos);
            int ax = (fx < 128) ? fx : 256 - fx;
            int m = ax * ax + r2yz;
            if (m >= NB * NB) continue;              // label >= 128: dropped
            int lab = (int)sqrtf((float)m);
            int posp = dr4((256 - fx) & 255);
            float2 a = tA[pos * 17 + zi];
            float2 b = tB[posp * 17 + colp];
            float F1r = 0.5f * (a.x + b.x);
            float F1i = 0.5f * (a.y - b.y);
            float F2r = 0.5f * (a.y + b.y);
            float F2i = 0.5f * (b.x - a.x);
            atomicAdd(&bs[w][lab],          wgt * (F1r * F2r + F1i * F2i));
            atomicAdd(&bs[w][NB + lab],     wgt * (F1r * F1r + F1i * F1i));
            atomicAdd(&bs[w][2 * NB + lab], wgt * (F2r * F2r + F2i * F2i));
        }
    }
    __syncthreads();

    float* dst = bins_s + (blockIdx.x & (NSPREAD - 1)) * (3 * NB);
    for (int i = t; i < 3 * NB; i += 256) {
        float v = bs[0][i] + bs[1][i] + bs[2][i] + bs[3][i];
        if (v != 0.f) atomicAdd(&dst[i], v);
    }
}

// ---------------------------------------------------------------------------
__global__ void zero_bins(float* bins)
{
    int t = blockIdx.x * blockDim.x + threadIdx.x;
    if (t < 2 * NSPREAD * 3 * NB) bins[t] = 0.f;
}

__global__ void finalize(const float* __restrict__ bins_s, float* __restrict__ out)
{
    __shared__ float red[256];
    const int t = threadIdx.x;
    const int b = t >> 7, bin = t & 127;
    const float* base = bins_s + (size_t)b * NSPREAD * 3 * NB;
    float num = 0.f, d1 = 0.f, d2 = 0.f;
    #pragma unroll
    for (int s = 0; s < NSPREAD; ++s) {
        num += base[s * 3 * NB + bin];
        d1  += base[s * 3 * NB + NB + bin];
        d2  += base[s * 3 * NB + 2 * NB + bin];
    }
    float fsc = num / sqrtf(d1 * d2 + 1e-8f);
    red[t] = fsc * fsc;
    __syncthreads();
    for (int s = 128; s > 0; s >>= 1) {
        if (t < s) red[t] += red[t + s];
        __syncthreads();
    }
    if (t == 0) out[0] = 1.f - red[0] / 256.f;
}

__global__ void ws_too_small(float* out) { out[0] = -1.0e9f; }

// ---------------------------------------------------------------------------
extern "C" void kernel_launch(void* const* d_in, const int* in_sizes, int n_in,
                              void* d_out, int out_size, void* d_ws, size_t ws_size,
                              hipStream_t stream)
{
    const float* ref  = (const float*)d_in[0];
    const float* pred = (const float*)d_in[1];
    float* out = (float*)d_out;

    const size_t volBytes = (size_t)VOL * sizeof(float2);   // 134,217,728
    const size_t binBytes = (size_t)2 * NSPREAD * 3 * NB * sizeof(float);
    if (ws_size < volBytes + binBytes) {
        ws_too_small<<<1, 1, 0, stream>>>(out);
        return;
    }
    float2* A     = (float2*)d_ws;
    float* bins_s = (float*)((char*)d_ws + volBytes);   // [2][NSPREAD][3*NB]

    zero_bins<<<(2 * NSPREAD * 3 * NB + 1023) / 1024, 1024, 0, stream>>>(bins_s);

    for (int b = 0; b < 2; ++b) {
        fftz_pack   <<<16384, 256, 0, stream>>>(ref + (size_t)b * VOL,
                                                pred + (size_t)b * VOL, A);
        fft_strided <<<4096, 256, 0, stream>>>(A, 256, 65536);          // y-pass
        fft_x_reduce<<<2048, 256, 0, stream>>>(A, bins_s + (size_t)b * NSPREAD * 3 * NB);
    }
    finalize<<<1, 256, 0, stream>>>(bins_s, out);
}